// Round 8
// baseline (215.215 us; speedup 1.0000x reference)
//
#include <hip/hip_runtime.h>

// ROUND 18 — persistent attn blocks + atomic work queue:
// R17 post-mortem: same-qt triples were makespan-WORST (3 blocks share one
// CU's pipes -> wall ~ sum, not max; CU sums 3..96). Deeper: occupancy ~16%
// = avg ~1.3 active blocks/CU — static maps leave CUs idle after their
// blocks finish. Fix: dynamic queue. 768 persistent blocks (3/CU resident)
// pull items via atomicAdd; item order worst-case-first: the 24 qt=0 items
// (each 32 iters w.p. ~0.5 via padded-row fallback — the hidden heavies)
// first, then qt=31..1 descending (tail <= 2 iters). Counter in ws tail,
// zeroed by transpose_vh (stream-ordered before attn). Items independent:
// disjoint O rows, read-only K/V; item-top __syncthreads fences LDS reuse.
// GEMMs/transposes unchanged (R15 structure).
// ws (bf16): qh[3145728] kh[3145728] vh[3145728] wt[4*589824] + ctr(int).

#define NEGV (-10000.0f)

typedef __attribute__((ext_vector_type(8))) short v8s;
typedef __attribute__((ext_vector_type(4))) float v4f;
typedef __attribute__((ext_vector_type(8))) unsigned short v8u;

#define GLDS16(g, l)                                            \
  __builtin_amdgcn_global_load_lds(                             \
      (const __attribute__((address_space(1))) void*)(g),       \
      (__attribute__((address_space(3))) void*)(l), 16, 0, 0)

// raw barrier: LDS ordering only; does NOT drain vmcnt.
#define BAR()                                                   \
  do {                                                          \
    asm volatile("s_waitcnt lgkmcnt(0)" ::: "memory");          \
    __builtin_amdgcn_s_barrier();                               \
    __builtin_amdgcn_sched_barrier(0);                          \
  } while (0)

__device__ __forceinline__ unsigned short f2bf(float f) {
  unsigned int u = __float_as_uint(f);
  u += 0x7FFFu + ((u >> 16) & 1u);   // RNE
  return (unsigned short)(u >> 16);
}

__device__ __forceinline__ unsigned int cvt_pk_bf16(float lo, float hi) {
  unsigned int r;
  asm("v_cvt_pk_bf16_f32 %0, %1, %2" : "=v"(r) : "v"(lo), "v"(hi));
  return r;
}

// ---------------------------------------------------------------- W transpose
__global__ __launch_bounds__(256) void transpose_w(
    const float* __restrict__ w0, const float* __restrict__ w1,
    const float* __restrict__ w2, const float* __restrict__ w3,
    unsigned short* __restrict__ t0, unsigned short* __restrict__ t1,
    unsigned short* __restrict__ t2, unsigned short* __restrict__ t3) {
  const float* w; unsigned short* t;
  switch (blockIdx.z) {
    case 0: w = w0; t = t0; break;
    case 1: w = w1; t = t1; break;
    case 2: w = w2; t = t2; break;
    default: w = w3; t = t3; break;
  }
  __shared__ unsigned short tile[32][33];
  const int tx = threadIdx.x & 31, ty = threadIdx.x >> 5;
  const int x0 = blockIdx.x * 32, y0 = blockIdx.y * 32;
#pragma unroll
  for (int j = 0; j < 4; j++)
    tile[ty + j * 8][tx] = f2bf(w[(size_t)(y0 + ty + j * 8) * 768 + x0 + tx]);
  __syncthreads();
#pragma unroll
  for (int j = 0; j < 4; j++)
    t[(size_t)(x0 + ty + j * 8) * 768 + y0 + tx] = tile[tx][ty + j * 8];
}

// ---------------------------------------------------------------- V transpose
// vh head-major [bh][s=2048][d=64] -> vht [bh][d=64][s=2048] (bf16).
// Also zeroes the attn work-queue counter (stream-ordered before attn).
__global__ __launch_bounds__(256) void transpose_vh(
    const unsigned short* __restrict__ vh, unsigned short* __restrict__ vht,
    int* __restrict__ ctr) {
  if (blockIdx.x == 0 && blockIdx.y == 0 && blockIdx.z == 0 &&
      threadIdx.x == 0)
    *ctr = 0;
  __shared__ unsigned short tile[32][33];
  const size_t hoff = (size_t)blockIdx.z * 2048 * 64;
  const unsigned short* src = vh + hoff;
  unsigned short* dst = vht + hoff;
  const int s0 = blockIdx.x * 32, d0 = blockIdx.y * 32;
  const int tx = threadIdx.x & 31, ty = threadIdx.x >> 5;
#pragma unroll
  for (int j = 0; j < 4; j++)
    tile[ty + j * 8][tx] = src[(size_t)(s0 + ty + j * 8) * 64 + d0 + tx];
  __syncthreads();
#pragma unroll
  for (int j = 0; j < 4; j++)
    dst[(size_t)(d0 + ty + j * 8) * 2048 + s0 + tx] = tile[tx][ty + j * 8];
}

// ---------------------------------------------------------------- GEMM core
// (R15 structure) 128x128 tile, 4 waves 2x2, 16x16x32 bf16 MFMA, BK=32,
// double-buffered LDS, one barrier per K-iter; GLDS16 staging issued before
// compute so latency hides under MFMAs.
template <bool ABF16HEAD, bool CF32ROW>
__device__ __forceinline__ void gemm_core(const void* __restrict__ A,
                                          const unsigned short* __restrict__ Wt,
                                          void* __restrict__ C) {
  const int tid = threadIdx.x;
  const int wave = tid >> 6, lane = tid & 63;
  const int quad = lane >> 4, l16 = lane & 15;
  const int wm = wave >> 1, wn = wave & 1;
  const int bm = blockIdx.x * 128, bn = blockIdx.y * 128;

  __shared__ __align__(16) unsigned short As[2][128 * 32];
  __shared__ __align__(16) unsigned short Bs[2][128 * 32];

  const int r0s = tid >> 2, c0s = (tid & 3) << 3;

  v4f acc[4][4];
#pragma unroll
  for (int i = 0; i < 4; i++)
#pragma unroll
    for (int j = 0; j < 4; j++) acc[i][j] = (v4f){0.f, 0.f, 0.f, 0.f};

  float4 nA00, nA01, nA10, nA11;

  auto issueB = [&](int kt, int nb) {
    const int c = kt * 32 + c0s;
    GLDS16(&Wt[(size_t)(bn + r0s) * 768 + c],
           &Bs[nb][(size_t)(wave * 64) * 8]);
    GLDS16(&Wt[(size_t)(bn + r0s + 64) * 768 + c],
           &Bs[nb][(size_t)(256 + wave * 64) * 8]);
  };
  auto issueA_glds = [&](int kt, int nb) {
    const int c = kt * 32 + c0s;
    const int rg0 = bm + r0s, rg1 = bm + r0s + 64;
    size_t a0 = ((size_t)((rg0 >> 11) * 12 + (c >> 6)) * 2048 +
                 (rg0 & 2047)) * 64 + (c & 63);
    size_t a1 = ((size_t)((rg1 >> 11) * 12 + (c >> 6)) * 2048 +
                 (rg1 & 2047)) * 64 + (c & 63);
    GLDS16((const unsigned short*)A + a0, &As[nb][(size_t)(wave * 64) * 8]);
    GLDS16((const unsigned short*)A + a1,
           &As[nb][(size_t)(256 + wave * 64) * 8]);
  };
  auto issueA_f32 = [&](int kt) {
    const float* Af = (const float*)A;
    const int c = kt * 32 + c0s;
    size_t a0 = (size_t)(bm + r0s) * 768 + c;
    size_t a1 = (size_t)(bm + r0s + 64) * 768 + c;
    nA00 = *(const float4*)(Af + a0);
    nA01 = *(const float4*)(Af + a0 + 4);
    nA10 = *(const float4*)(Af + a1);
    nA11 = *(const float4*)(Af + a1 + 4);
  };
  auto writeA_f32 = [&](int nb) {
    v8u t0, t1;
    t0[0] = f2bf(nA00.x); t0[1] = f2bf(nA00.y);
    t0[2] = f2bf(nA00.z); t0[3] = f2bf(nA00.w);
    t0[4] = f2bf(nA01.x); t0[5] = f2bf(nA01.y);
    t0[6] = f2bf(nA01.z); t0[7] = f2bf(nA01.w);
    t1[0] = f2bf(nA10.x); t1[1] = f2bf(nA10.y);
    t1[2] = f2bf(nA10.z); t1[3] = f2bf(nA10.w);
    t1[4] = f2bf(nA11.x); t1[5] = f2bf(nA11.y);
    t1[6] = f2bf(nA11.z); t1[7] = f2bf(nA11.w);
    *(uint4*)&As[nb][r0s * 32 + c0s] = *(uint4*)&t0;
    *(uint4*)&As[nb][(r0s + 64) * 32 + c0s] = *(uint4*)&t1;
  };

  if (ABF16HEAD) {
    issueA_glds(0, 0);
  } else {
    issueA_f32(0);
  }
  issueB(0, 0);
  if (!ABF16HEAD) writeA_f32(0);
  __syncthreads();

  for (int kt = 0; kt < 24; kt++) {
    const int cur = kt & 1, nxt = cur ^ 1;

    if (kt < 23) {
      if (ABF16HEAD) issueA_glds(kt + 1, nxt);
      else issueA_f32(kt + 1);
      issueB(kt + 1, nxt);
    }

    v8s aF[4], bF[4];
#pragma unroll
    for (int mt = 0; mt < 4; mt++)
      aF[mt] =
          *(const v8s*)&As[cur][(wm * 64 + mt * 16 + l16) * 32 + quad * 8];
#pragma unroll
    for (int nt = 0; nt < 4; nt++)
      bF[nt] =
          *(const v8s*)&Bs[cur][(wn * 64 + nt * 16 + l16) * 32 + quad * 8];
#pragma unroll
    for (int mt = 0; mt < 4; mt++)
#pragma unroll
      for (int nt = 0; nt < 4; nt++)
        acc[mt][nt] = __builtin_amdgcn_mfma_f32_16x16x32_bf16(
            aF[mt], bF[nt], acc[mt][nt], 0, 0, 0);

    if (kt < 23 && !ABF16HEAD) writeA_f32(nxt);
    __syncthreads();
  }

#pragma unroll
  for (int mt = 0; mt < 4; mt++) {
#pragma unroll
    for (int i = 0; i < 4; i++) {
      int row = bm + wm * 64 + mt * 16 + quad * 4 + i;
#pragma unroll
      for (int nt = 0; nt < 4; nt++) {
        int col = bn + wn * 64 + nt * 16 + l16;
        if (CF32ROW) {
          ((float*)C)[(size_t)row * 768 + col] = acc[mt][nt][i];
        } else {
          size_t off = ((size_t)((row >> 11) * 12 + (col >> 6)) * 2048 +
                        (row & 2047)) * 64 + (col & 63);
          ((unsigned short*)C)[off] = f2bf(acc[mt][nt][i]);
        }
      }
    }
  }
}

__global__ __launch_bounds__(256) void gemm_qkv(
    const float* __restrict__ xq, const float* __restrict__ xk,
    const float* __restrict__ xv, const unsigned short* __restrict__ wqt,
    const unsigned short* __restrict__ wkt, const unsigned short* __restrict__ wvt,
    unsigned short* __restrict__ qh, unsigned short* __restrict__ kh,
    unsigned short* __restrict__ vh) {
  const float* A; const unsigned short* Wt; unsigned short* C;
  switch (blockIdx.z) {
    case 0: A = xq; Wt = wqt; C = qh; break;
    case 1: A = xk; Wt = wkt; C = kh; break;
    default: A = xv; Wt = wvt; C = vh; break;
  }
  gemm_core<false, false>((const void*)A, Wt, (void*)C);
}

__global__ __launch_bounds__(256) void gemm_o(
    const unsigned short* __restrict__ oat, const unsigned short* __restrict__ wot,
    float* __restrict__ out) {
  gemm_core<true, true>((const void*)oat, wot, (void*)out);
}

// ---------------------------------------------------------------- attention
// Persistent blocks + atomic work queue. Item i -> (qt,bh): i<24 -> qt=0
// (potentially 32-iter fallback, scheduled first), else qt=31-(i-24)/24
// descending, bh=(i-24)%24. Per item: 4 waves x 16 q-rows, dbuf K/V, ONE raw
// barrier per tile, swapped QK^T (S^T = mfma(K,Q)), defer-max, ballot pad
// mask, MFMA row-sum. Future tiles only if some row fully padded (bit-exact).
__global__ __launch_bounds__(256) void attn_kernel(
    const unsigned short* __restrict__ qh, const unsigned short* __restrict__ kh,
    const unsigned short* __restrict__ vht, const int* __restrict__ attn_mask,
    const int* __restrict__ mask_future, int* __restrict__ ctr,
    unsigned short* __restrict__ o) {
  const int S = 2048, HD = 64, NH = 12;

  const int tid = threadIdx.x;
  const int wave = tid >> 6, lane = tid & 63;
  const int quad = lane >> 4, l16 = lane & 15;

  __shared__ __align__(16) unsigned short Ks[2][64 * 72];
  __shared__ __align__(16) unsigned short Vt[2][64 * 72];   // V^T [d][k]
  __shared__ __align__(16) unsigned short Ps[4][16 * 72];   // P [qrow][key]
  __shared__ int s_flag;
  __shared__ int s_item;

  const int mf = mask_future[0];
  const int r0 = tid >> 3, c0s = (tid & 7) << 3;

  v8s ones;   // bf16 1.0 x8 -> all-ones B-frag for the row-sum MFMA
#pragma unroll
  for (int j = 0; j < 8; j++) ones[j] = (short)0x3F80;

  while (true) {
    if (tid == 0) s_item = atomicAdd(ctr, 1);
    __syncthreads();   // broadcast item; also fences LDS reuse across items
    const int it = s_item;
    if (it >= 768) break;

    int qt, bh;
    if (it < 24) { qt = 0; bh = it; }
    else { int j = it - 24; int r = j / 24; qt = 31 - r; bh = j - r * 24; }
    const int b = bh / NH, h = bh % NH;

    if (tid == 0) s_flag = 0;

    const size_t head_off = (size_t)(b * NH + h) * S * HD;
    const unsigned short* Kb = kh + head_off;
    const unsigned short* Vb = vht + head_off;   // [d=64][s=2048] per head

    const int qrow_l = qt * 64 + wave * 16 + l16;
    v8s aQ[2];
    {
      const unsigned short* qp = qh + head_off + (size_t)qrow_l * HD + quad * 8;
      aQ[0] = *(const v8s*)(qp);
      aQ[1] = *(const v8s*)(qp + 32);
    }
    const int qbase_D = qt * 64 + wave * 16 + quad * 4;

    float m_i = -1e30f;
    v4f accO[4], accL;
    accL = (v4f){0.f, 0.f, 0.f, 0.f};
#pragma unroll
    for (int dt = 0; dt < 4; dt++) accO[dt] = (v4f){0.f, 0.f, 0.f, 0.f};

    const int kt_causal = mf ? qt : (S / 64 - 1);

    auto nexttile = [&](int t) -> int {
      if (t < kt_causal) return t + 1;
      if (t == kt_causal) return (mf && kt_causal < S / 64 - 1) ? t + 1 : -1;
      return (t < S / 64 - 1) ? t + 1 : -1;
    };

    uint4 pk0, pk1, pv0, pv1;
    int pmv = 0;
    unsigned long long msk0 = 0, msk1 = 0;
    int rtile = -1, stile = -1;

    auto prefetch = [&](int kt) {
      const uint4* srck = (const uint4*)(Kb + (size_t)kt * 64 * HD);
      pk0 = srck[tid];
      pk1 = srck[256 + tid];
      const unsigned short* vp = Vb + (size_t)r0 * S + kt * 64 + c0s;
      pv0 = *(const uint4*)vp;
      pv1 = *(const uint4*)(vp + (size_t)32 * S);
      pmv = attn_mask[b * S + kt * 64 + lane];
      rtile = kt;
    };

    auto stage = [&](int kb) {
      *(uint4*)&Ks[kb][r0 * 72 + c0s] = pk0;
      *(uint4*)&Ks[kb][(r0 + 32) * 72 + c0s] = pk1;
      *(uint4*)&Vt[kb][r0 * 72 + c0s] = pv0;
      *(uint4*)&Vt[kb][(r0 + 32) * 72 + c0s] = pv1;
      unsigned long long mk = __ballot(pmv != 0);
      if (kb) msk1 = mk; else msk0 = mk;
    };

    for (int phase = 0; phase < 2; phase++) {
      int kt_lo, kt_hi;
      if (phase == 0) { kt_lo = 0; kt_hi = kt_causal; }
      else {
        if (m_i < -5000.f) s_flag = 1;  // benign race (0->1)
        __syncthreads();
        if (!s_flag) break;
        kt_lo = kt_causal + 1; kt_hi = S / 64 - 1;
        if (kt_lo > kt_hi) break;
      }

      if (stile != kt_lo) {          // cold start (phase 0; phase 1 is warm)
        if (rtile != kt_lo) prefetch(kt_lo);
        stage(kt_lo & 1);
        stile = kt_lo;
        int nx = nexttile(kt_lo);
        if (nx >= 0) prefetch(nx);
      }

      for (int kt = kt_lo; kt <= kt_hi; kt++) {
        BAR();  // buf[kt&1] visible; buf[kt&1]^1 free; prefetch NOT drained

        int nkt = nexttile(kt);
        if (nkt >= 0 && stile != nkt) {
          stage(nkt & 1);
          stile = nkt;
          int n2 = nexttile(nkt);
          if (n2 >= 0) prefetch(n2);
        }

        const int kb = kt & 1;
        const unsigned short* KsB = Ks[kb];
        const unsigned short* VtB = Vt[kb];
        const unsigned long long mk = kb ? msk1 : msk0;

        // S^T = mfma(K, Q): sc[nt][i] = S[qrow=l16][key=kt*64+nt*16+quad*4+i]
        v4f sc[4];
        __builtin_amdgcn_s_setprio(1);
#pragma unroll
        for (int nt = 0; nt < 4; nt++) {
          const unsigned short* kp = &KsB[(nt * 16 + l16) * 72 + quad * 8];
          v8s k0 = *(const v8s*)kp;
          v8s k1 = *(const v8s*)(kp + 32);
          v4f z = (v4f){0.f, 0.f, 0.f, 0.f};
          z = __builtin_amdgcn_mfma_f32_16x16x32_bf16(k0, aQ[0], z, 0, 0, 0);
          z = __builtin_amdgcn_mfma_f32_16x16x32_bf16(k1, aQ[1], z, 0, 0, 0);
          sc[nt] = z;
        }
        __builtin_amdgcn_s_setprio(0);

        // scale + causal (additive) + padding (replace) — exact ref semantics
#pragma unroll
        for (int nt = 0; nt < 4; nt++) {
#pragma unroll
          for (int i = 0; i < 4; i++) {
            int kid = nt * 16 + quad * 4 + i;
            int key = kt * 64 + kid;
            float v = sc[nt][i] * 0.125f;
            v += (mf && (key > qrow_l)) ? NEGV : 0.f;
            v = ((mk >> kid) & 1ull) ? v : NEGV;
            sc[nt][i] = v;
          }
        }

        // row max: 15 in-lane fmax + 2 cross-quad shuffles (row = l16)
        float mx;
        {
          float a = fmaxf(fmaxf(sc[0][0], sc[0][1]), fmaxf(sc[0][2], sc[0][3]));
          float b2 = fmaxf(fmaxf(sc[1][0], sc[1][1]), fmaxf(sc[1][2], sc[1][3]));
          float c = fmaxf(fmaxf(sc[2][0], sc[2][1]), fmaxf(sc[2][2], sc[2][3]));
          float d = fmaxf(fmaxf(sc[3][0], sc[3][1]), fmaxf(sc[3][2], sc[3][3]));
          mx = fmaxf(fmaxf(a, b2), fmaxf(c, d));
        }
        mx = fmaxf(mx, __shfl_xor(mx, 16));
        mx = fmaxf(mx, __shfl_xor(mx, 32));

        // T13 defer-max (exact: row-uniform scale cancels in normalize)
        if (!__all(mx - m_i <= 8.0f)) {
          float mnew = fmaxf(m_i, mx);
          float alpha = __expf(m_i - mnew);
          m_i = mnew;
          float a0 = __shfl(alpha, quad * 4 + 0);
          float a1 = __shfl(alpha, quad * 4 + 1);
          float a2 = __shfl(alpha, quad * 4 + 2);
          float a3 = __shfl(alpha, quad * 4 + 3);
#pragma unroll
          for (int dt = 0; dt < 4; dt++) {
            accO[dt][0] *= a0; accO[dt][1] *= a1;
            accO[dt][2] *= a2; accO[dt][3] *= a3;
          }
          accL[0] *= a0; accL[1] *= a1; accL[2] *= a2; accL[3] *= a3;
        }

        // exp + pack to bf16 pairs + 4x ds_write_b64 into P[qrow l16][key]
#pragma unroll
        for (int nt = 0; nt < 4; nt++) {
#pragma unroll
          for (int i = 0; i < 4; i++)
            sc[nt][i] = __expf(sc[nt][i] - m_i);
          uint2 w;
          w.x = cvt_pk_bf16(sc[nt][0], sc[nt][1]);
          w.y = cvt_pk_bf16(sc[nt][2], sc[nt][3]);
          *(uint2*)&Ps[wave][l16 * 72 + nt * 16 + quad * 4] = w;
        }

        __builtin_amdgcn_s_setprio(1);
#pragma unroll
        for (int ks = 0; ks < 2; ks++) {
          v8s aP = *(const v8s*)&Ps[wave][l16 * 72 + ks * 32 + quad * 8];
          accL =
              __builtin_amdgcn_mfma_f32_16x16x32_bf16(aP, ones, accL, 0, 0, 0);
#pragma unroll
          for (int dt = 0; dt < 4; dt++) {
            v8s bV =
                *(const v8s*)&VtB[(dt * 16 + l16) * 72 + ks * 32 + quad * 8];
            accO[dt] = __builtin_amdgcn_mfma_f32_16x16x32_bf16(aP, bV,
                                                               accO[dt], 0, 0, 0);
          }
        }
        __builtin_amdgcn_s_setprio(0);
      }
      if (phase == 0) __syncthreads();  // all waves done before flag vote
    }

    // normalize + store O bf16 head-major over own Q region (in place)
#pragma unroll
    for (int i = 0; i < 4; i++) {
      float inv = 1.f / accL[i];
      int qr = qbase_D + i;
      size_t base = head_off + (size_t)qr * HD;
#pragma unroll
      for (int dt = 0; dt < 4; dt++)
        o[base + dt * 16 + l16] = f2bf(accO[dt][i] * inv);
    }
  }
}

// ---------------------------------------------------------------- launch
extern "C" void kernel_launch(void* const* d_in, const int* in_sizes, int n_in,
                              void* d_out, int out_size, void* d_ws, size_t ws_size,
                              hipStream_t stream) {
  const float* q  = (const float*)d_in[0];
  const float* k  = (const float*)d_in[1];
  const float* v  = (const float*)d_in[2];
  const int* amask = (const int*)d_in[3];
  const float* Wq = (const float*)d_in[4];
  const float* Wk = (const float*)d_in[5];
  const float* Wv = (const float*)d_in[6];
  const float* Wo = (const float*)d_in[7];
  const int* mf  = (const int*)d_in[8];
  float* out = (float*)d_out;

  unsigned short* ws = (unsigned short*)d_ws;
  unsigned short* qh = ws;                  // O overwrites qh after attention
  unsigned short* kh = qh + 3145728;
  unsigned short* vh = kh + 3145728;
  unsigned short* wqt = vh + 3145728;
  unsigned short* wkt = wqt + 589824;
  unsigned short* wvt = wkt + 589824;
  unsigned short* wot = wvt + 589824;
  int* ctr = (int*)(wot + 589824);          // work-queue counter (4 B)
  // vht (6.3 MB bf16) lives in d_out (12.6 MB) — dead until gemm_o overwrites.
  unsigned short* vht = (unsigned short*)d_out;

  transpose_w<<<dim3(24, 24, 4), 256, 0, stream>>>(Wq, Wk, Wv, Wo,
                                                   wqt, wkt, wvt, wot);
  gemm_qkv<<<dim3(32, 6, 3), 256, 0, stream>>>(q, k, v, wqt, wkt, wvt,
                                               qh, kh, vh);
  transpose_vh<<<dim3(64, 2, 24), 256, 0, stream>>>(vh, vht, ctr);
  attn_kernel<<<dim3(32, 24), 256, 0, stream>>>(qh, kh, vht, amask, mf, ctr,
                                                qh);
  gemm_o<<<dim3(32, 6), 256, 0, stream>>>(qh, wot, out);
}

// Round 9
// 209.794 us; speedup vs baseline: 1.0258x; 1.0258x over previous
//
#include <hip/hip_runtime.h>

// ROUND 19 — counted-vmcnt GEMM pipeline (proper T4) + attn revert to R16:
// (1) attn: R18's dynamic queue hurt (79us; FETCH 9.3->47MB — queue items
//     lose XCD L2 affinity). Revert to the best-measured config: R11 snake
//     map + R16 internals (raw BAR, swapped QK^T, defer-max) = 66.8us.
// (2) GEMMs: __syncthreads drains vmcnt(0) -> R15's pipeline gave tile k+1
//     only ~300cyc cover. Proper T4: 3-buffer LDS, issue tile k+2 at iter k
//     (2-iter cover), barrier = "s_waitcnt vmcnt(N) lgkmcnt(0); s_barrier;
//     sched_barrier" with N = tile k+2's in-flight ops (6 fp32-A path, 4
//     bf16-A path) so tile k+1's loads are complete but k+2's stay in
//     flight. fp32-A via 2 parity reg sets (load at k, ds_write at k+1).
// ws (bf16): qh[3145728] kh[3145728] vh[3145728] wt[4*589824] = 23.6 MB.
// vht (6.3 MB) lives in d_out (12.6 MB); gemm_o overwrites d_out at the end.

#define NEGV (-10000.0f)

typedef __attribute__((ext_vector_type(8))) short v8s;
typedef __attribute__((ext_vector_type(4))) float v4f;
typedef __attribute__((ext_vector_type(8))) unsigned short v8u;

#define GLDS16(g, l)                                            \
  __builtin_amdgcn_global_load_lds(                             \
      (const __attribute__((address_space(1))) void*)(g),       \
      (__attribute__((address_space(3))) void*)(l), 16, 0, 0)

// raw barrier: LDS ordering only; does NOT drain vmcnt (attn).
#define BAR()                                                   \
  do {                                                          \
    asm volatile("s_waitcnt lgkmcnt(0)" ::: "memory");          \
    __builtin_amdgcn_s_barrier();                               \
    __builtin_amdgcn_sched_barrier(0);                          \
  } while (0)

// counted barrier: allow Nstr vector-mem ops to stay in flight (GEMM).
#define GBARN(Nstr)                                                     \
  do {                                                                  \
    asm volatile("s_waitcnt vmcnt(" Nstr ") lgkmcnt(0)" ::: "memory");  \
    __builtin_amdgcn_s_barrier();                                       \
    __builtin_amdgcn_sched_barrier(0);                                  \
  } while (0)

__device__ __forceinline__ unsigned short f2bf(float f) {
  unsigned int u = __float_as_uint(f);
  u += 0x7FFFu + ((u >> 16) & 1u);   // RNE
  return (unsigned short)(u >> 16);
}

__device__ __forceinline__ unsigned int cvt_pk_bf16(float lo, float hi) {
  unsigned int r;
  asm("v_cvt_pk_bf16_f32 %0, %1, %2" : "=v"(r) : "v"(lo), "v"(hi));
  return r;
}

// ---------------------------------------------------------------- W transpose
__global__ __launch_bounds__(256) void transpose_w(
    const float* __restrict__ w0, const float* __restrict__ w1,
    const float* __restrict__ w2, const float* __restrict__ w3,
    unsigned short* __restrict__ t0, unsigned short* __restrict__ t1,
    unsigned short* __restrict__ t2, unsigned short* __restrict__ t3) {
  const float* w; unsigned short* t;
  switch (blockIdx.z) {
    case 0: w = w0; t = t0; break;
    case 1: w = w1; t = t1; break;
    case 2: w = w2; t = t2; break;
    default: w = w3; t = t3; break;
  }
  __shared__ unsigned short tile[32][33];
  const int tx = threadIdx.x & 31, ty = threadIdx.x >> 5;
  const int x0 = blockIdx.x * 32, y0 = blockIdx.y * 32;
#pragma unroll
  for (int j = 0; j < 4; j++)
    tile[ty + j * 8][tx] = f2bf(w[(size_t)(y0 + ty + j * 8) * 768 + x0 + tx]);
  __syncthreads();
#pragma unroll
  for (int j = 0; j < 4; j++)
    t[(size_t)(x0 + ty + j * 8) * 768 + y0 + tx] = tile[tx][ty + j * 8];
}

// ---------------------------------------------------------------- V transpose
// vh head-major [bh][s=2048][d=64] -> vht [bh][d=64][s=2048] (bf16).
__global__ __launch_bounds__(256) void transpose_vh(
    const unsigned short* __restrict__ vh, unsigned short* __restrict__ vht) {
  __shared__ unsigned short tile[32][33];
  const size_t hoff = (size_t)blockIdx.z * 2048 * 64;
  const unsigned short* src = vh + hoff;
  unsigned short* dst = vht + hoff;
  const int s0 = blockIdx.x * 32, d0 = blockIdx.y * 32;
  const int tx = threadIdx.x & 31, ty = threadIdx.x >> 5;
#pragma unroll
  for (int j = 0; j < 4; j++)
    tile[ty + j * 8][tx] = src[(size_t)(s0 + ty + j * 8) * 64 + d0 + tx];
  __syncthreads();
#pragma unroll
  for (int j = 0; j < 4; j++)
    dst[(size_t)(d0 + ty + j * 8) * 2048 + s0 + tx] = tile[tx][ty + j * 8];
}

// ---------------------------------------------------------------- GEMM core
// 128x128 tile, 4 waves 2x2, 16x16x32 bf16 MFMA, BK=32. 3-stage pipeline:
// tile k+2 issued at iter k (2-iter cover); counted-vmcnt barriers keep
// tile k+2's loads in flight across the barrier (only k+1's must land).
template <bool ABF16HEAD, bool CF32ROW>
__device__ __forceinline__ void gemm_core(const void* __restrict__ A,
                                          const unsigned short* __restrict__ Wt,
                                          void* __restrict__ C) {
  const int tid = threadIdx.x;
  const int wave = tid >> 6, lane = tid & 63;
  const int quad = lane >> 4, l16 = lane & 15;
  const int wm = wave >> 1, wn = wave & 1;
  const int bm = blockIdx.x * 128, bn = blockIdx.y * 128;

  __shared__ __align__(16) unsigned short As[3][128 * 32];
  __shared__ __align__(16) unsigned short Bs[3][128 * 32];

  const int r0s = tid >> 2, c0s = (tid & 3) << 3;

  v4f acc[4][4];
#pragma unroll
  for (int i = 0; i < 4; i++)
#pragma unroll
    for (int j = 0; j < 4; j++) acc[i][j] = (v4f){0.f, 0.f, 0.f, 0.f};

  // fp32-A parity register sets (static names, rule #20)
  struct StgA { float4 x0, x1, x2, x3; };
  StgA sA, sB;

  auto issueB = [&](int kt, int nb) {
    const int c = kt * 32 + c0s;
    GLDS16(&Wt[(size_t)(bn + r0s) * 768 + c],
           &Bs[nb][(size_t)(wave * 64) * 8]);
    GLDS16(&Wt[(size_t)(bn + r0s + 64) * 768 + c],
           &Bs[nb][(size_t)(256 + wave * 64) * 8]);
  };
  auto issueA_glds = [&](int kt, int nb) {
    const int c = kt * 32 + c0s;
    const int rg0 = bm + r0s, rg1 = bm + r0s + 64;
    size_t a0 = ((size_t)((rg0 >> 11) * 12 + (c >> 6)) * 2048 +
                 (rg0 & 2047)) * 64 + (c & 63);
    size_t a1 = ((size_t)((rg1 >> 11) * 12 + (c >> 6)) * 2048 +
                 (rg1 & 2047)) * 64 + (c & 63);
    GLDS16((const unsigned short*)A + a0, &As[nb][(size_t)(wave * 64) * 8]);
    GLDS16((const unsigned short*)A + a1,
           &As[nb][(size_t)(256 + wave * 64) * 8]);
  };
  auto loadF = [&](StgA& s, int kt) {
    const float* Af = (const float*)A;
    const int c = kt * 32 + c0s;
    size_t a0 = (size_t)(bm + r0s) * 768 + c;
    size_t a1 = (size_t)(bm + r0s + 64) * 768 + c;
    s.x0 = *(const float4*)(Af + a0);
    s.x1 = *(const float4*)(Af + a0 + 4);
    s.x2 = *(const float4*)(Af + a1);
    s.x3 = *(const float4*)(Af + a1 + 4);
  };
  auto writeA = [&](StgA& s, int nb) {
    v8u t0, t1;
    t0[0] = f2bf(s.x0.x); t0[1] = f2bf(s.x0.y);
    t0[2] = f2bf(s.x0.z); t0[3] = f2bf(s.x0.w);
    t0[4] = f2bf(s.x1.x); t0[5] = f2bf(s.x1.y);
    t0[6] = f2bf(s.x1.z); t0[7] = f2bf(s.x1.w);
    t1[0] = f2bf(s.x2.x); t1[1] = f2bf(s.x2.y);
    t1[2] = f2bf(s.x2.z); t1[3] = f2bf(s.x2.w);
    t1[4] = f2bf(s.x3.x); t1[5] = f2bf(s.x3.y);
    t1[6] = f2bf(s.x3.z); t1[7] = f2bf(s.x3.w);
    *(uint4*)&As[nb][r0s * 32 + c0s] = *(uint4*)&t0;
    *(uint4*)&As[nb][(r0s + 64) * 32 + c0s] = *(uint4*)&t1;
  };
  auto compute = [&](int cur) {
    v8s aF[4], bF[4];
#pragma unroll
    for (int mt = 0; mt < 4; mt++)
      aF[mt] =
          *(const v8s*)&As[cur][(wm * 64 + mt * 16 + l16) * 32 + quad * 8];
#pragma unroll
    for (int nt = 0; nt < 4; nt++)
      bF[nt] =
          *(const v8s*)&Bs[cur][(wn * 64 + nt * 16 + l16) * 32 + quad * 8];
#pragma unroll
    for (int mt = 0; mt < 4; mt++)
#pragma unroll
      for (int nt = 0; nt < 4; nt++)
        acc[mt][nt] = __builtin_amdgcn_mfma_f32_16x16x32_bf16(
            aF[mt], bF[nt], acc[mt][nt], 0, 0, 0);
  };

  // ---- prologue: tiles 0 and 1 ----
  if (ABF16HEAD) {
    issueA_glds(0, 0); issueB(0, 0);
    issueA_glds(1, 1); issueB(1, 1);
    GBARN("4");   // tile0 done; tile1's 4 stay in flight
  } else {
    loadF(sA, 0);      // tile0 -> sA
    loadF(sB, 1);      // tile1 -> sB
    issueB(0, 0); issueB(1, 1);
    writeA(sA, 0);     // waits tile0's A loads (cold, once)
    GBARN("2");        // B0 done; B1's 2 stay in flight
  }

  // ---- main loop, unrolled x2 for static parity sets ----
  for (int kt = 0; kt < 24; kt += 2) {
    // body A: compute tile kt; issue kt+2 (into sA / bufs); write tile kt+1
    if (kt + 2 < 24) {
      if (ABF16HEAD) issueA_glds(kt + 2, (kt + 2) % 3);
      else loadF(sA, kt + 2);
      issueB(kt + 2, (kt + 2) % 3);
    }
    if (!ABF16HEAD) writeA(sB, (kt + 1) % 3);   // tile kt+1 (1-iter-old regs)
    compute(kt % 3);
    if (kt + 2 < 24) {
      if (ABF16HEAD) { GBARN("4"); } else { GBARN("6"); }
    } else {
      GBARN("0");
    }

    // body B: compute tile kt+1; issue kt+3 (into sB); write tile kt+2
    if (kt + 3 < 24) {
      if (ABF16HEAD) issueA_glds(kt + 3, (kt + 3) % 3);
      else loadF(sB, kt + 3);
      issueB(kt + 3, (kt + 3) % 3);
    }
    if (!ABF16HEAD && kt + 2 < 24) writeA(sA, (kt + 2) % 3);
    compute((kt + 1) % 3);
    if (kt + 3 < 24) {
      if (ABF16HEAD) { GBARN("4"); } else { GBARN("6"); }
    } else {
      GBARN("0");
    }
  }

  // epilogue: C/D layout row(m) = quad*4+i, col(n) = l16
#pragma unroll
  for (int mt = 0; mt < 4; mt++) {
#pragma unroll
    for (int i = 0; i < 4; i++) {
      int row = bm + wm * 64 + mt * 16 + quad * 4 + i;
#pragma unroll
      for (int nt = 0; nt < 4; nt++) {
        int col = bn + wn * 64 + nt * 16 + l16;
        if (CF32ROW) {
          ((float*)C)[(size_t)row * 768 + col] = acc[mt][nt][i];
        } else {
          size_t off = ((size_t)((row >> 11) * 12 + (col >> 6)) * 2048 +
                        (row & 2047)) * 64 + (col & 63);
          ((unsigned short*)C)[off] = f2bf(acc[mt][nt][i]);
        }
      }
    }
  }
}

__global__ __launch_bounds__(256) void gemm_qkv(
    const float* __restrict__ xq, const float* __restrict__ xk,
    const float* __restrict__ xv, const unsigned short* __restrict__ wqt,
    const unsigned short* __restrict__ wkt, const unsigned short* __restrict__ wvt,
    unsigned short* __restrict__ qh, unsigned short* __restrict__ kh,
    unsigned short* __restrict__ vh) {
  const float* A; const unsigned short* Wt; unsigned short* C;
  switch (blockIdx.z) {
    case 0: A = xq; Wt = wqt; C = qh; break;
    case 1: A = xk; Wt = wkt; C = kh; break;
    default: A = xv; Wt = wvt; C = vh; break;
  }
  gemm_core<false, false>((const void*)A, Wt, (void*)C);
}

__global__ __launch_bounds__(256) void gemm_o(
    const unsigned short* __restrict__ oat, const unsigned short* __restrict__ wot,
    float* __restrict__ out) {
  gemm_core<true, true>((const void*)oat, wot, (void*)out);
}

// ---------------------------------------------------------------- attention
// (R16 config, best measured 66.8us) grid (32,24); LPT snake remap; 4 waves
// x 16 q-rows, dbuf K/V, ONE raw barrier per tile. Swapped QK^T: S^T =
// mfma(K, Q). Causal tiles kt=0..qt always; future tiles only if some row's
// visible window fully padded (bit-exact skip).
__global__ __launch_bounds__(256) void attn_kernel(
    const unsigned short* __restrict__ qh, const unsigned short* __restrict__ kh,
    const unsigned short* __restrict__ vht, const int* __restrict__ attn_mask,
    const int* __restrict__ mask_future, unsigned short* __restrict__ o) {
  const int S = 2048, HD = 64, NH = 12;

  const int nlin = blockIdx.x + 32 * blockIdx.y;
  const int m_ = nlin & 255, t_ = nlin >> 8;
  const int i_ = (t_ == 1) ? (511 - m_) : (t_ * 256 + m_);
  const int qt = 31 - i_ / 24;
  const int bh = i_ - (i_ / 24) * 24;
  const int b = bh / NH, h = bh % NH;

  const int tid = threadIdx.x;
  const int wave = tid >> 6, lane = tid & 63;
  const int quad = lane >> 4, l16 = lane & 15;

  __shared__ __align__(16) unsigned short Ks[2][64 * 72];
  __shared__ __align__(16) unsigned short Vt[2][64 * 72];   // V^T [d][k]
  __shared__ __align__(16) unsigned short Ps[4][16 * 72];   // P [qrow][key]
  __shared__ int s_flag;

  const size_t head_off = (size_t)(b * NH + h) * S * HD;
  const unsigned short* Kb = kh + head_off;
  const unsigned short* Vb = vht + head_off;   // [d=64][s=2048] per head

  const int mf = mask_future[0];
  if (tid == 0) s_flag = 0;

  const int qrow_l = qt * 64 + wave * 16 + l16;   // this lane's q-row
  v8s aQ[2];
  {
    const unsigned short* qp = qh + head_off + (size_t)qrow_l * HD + quad * 8;
    aQ[0] = *(const v8s*)(qp);
    aQ[1] = *(const v8s*)(qp + 32);
  }
  const int qbase_D = qt * 64 + wave * 16 + quad * 4;  // accO/accL row space

  float m_i = -1e30f;           // running max for q-row l16 (lane-local)
  v4f accO[4], accL;
  accL = (v4f){0.f, 0.f, 0.f, 0.f};
#pragma unroll
  for (int dt = 0; dt < 4; dt++) accO[dt] = (v4f){0.f, 0.f, 0.f, 0.f};

  v8s ones;   // bf16 1.0 x8 -> all-ones B-frag for the row-sum MFMA
#pragma unroll
  for (int j = 0; j < 8; j++) ones[j] = (short)0x3F80;

  const int kt_causal = mf ? qt : (S / 64 - 1);
  const int r0 = tid >> 3, c0s = (tid & 7) << 3;

  auto nexttile = [&](int t) -> int {
    if (t < kt_causal) return t + 1;
    if (t == kt_causal) return (mf && kt_causal < S / 64 - 1) ? t + 1 : -1;
    return (t < S / 64 - 1) ? t + 1 : -1;
  };

  uint4 pk0, pk1, pv0, pv1;
  int pmv = 0;
  unsigned long long msk0 = 0, msk1 = 0;   // staged pad masks (dbuf)
  int rtile = -1, stile = -1;

  auto prefetch = [&](int kt) {
    const uint4* srck = (const uint4*)(Kb + (size_t)kt * 64 * HD);
    pk0 = srck[tid];
    pk1 = srck[256 + tid];
    const unsigned short* vp = Vb + (size_t)r0 * S + kt * 64 + c0s;
    pv0 = *(const uint4*)vp;
    pv1 = *(const uint4*)(vp + (size_t)32 * S);
    pmv = attn_mask[b * S + kt * 64 + lane];
    rtile = kt;
  };

  auto stage = [&](int kb) {
    *(uint4*)&Ks[kb][r0 * 72 + c0s] = pk0;
    *(uint4*)&Ks[kb][(r0 + 32) * 72 + c0s] = pk1;
    *(uint4*)&Vt[kb][r0 * 72 + c0s] = pv0;
    *(uint4*)&Vt[kb][(r0 + 32) * 72 + c0s] = pv1;
    unsigned long long mk = __ballot(pmv != 0);
    if (kb) msk1 = mk; else msk0 = mk;
  };

  for (int phase = 0; phase < 2; phase++) {
    int kt_lo, kt_hi;
    if (phase == 0) { kt_lo = 0; kt_hi = kt_causal; }
    else {
      if (m_i < -5000.f) s_flag = 1;  // benign race (0->1)
      __syncthreads();
      if (!s_flag) break;
      kt_lo = kt_causal + 1; kt_hi = S / 64 - 1;
      if (kt_lo > kt_hi) break;
    }

    if (stile != kt_lo) {            // cold start (phase 0; phase 1 is warm)
      if (rtile != kt_lo) prefetch(kt_lo);
      stage(kt_lo & 1);
      stile = kt_lo;
      int nx = nexttile(kt_lo);
      if (nx >= 0) prefetch(nx);
    }

    for (int kt = kt_lo; kt <= kt_hi; kt++) {
      BAR();  // buf[kt&1] visible; buf[kt&1]^1 free; prefetch NOT drained

      int nkt = nexttile(kt);
      if (nkt >= 0 && stile != nkt) {
        stage(nkt & 1);
        stile = nkt;
        int n2 = nexttile(nkt);
        if (n2 >= 0) prefetch(n2);
      }

      const int kb = kt & 1;
      const unsigned short* KsB = Ks[kb];
      const unsigned short* VtB = Vt[kb];
      const unsigned long long mk = kb ? msk1 : msk0;

      // S^T = mfma(K, Q): sc[nt][i] = S[qrow=l16][key=kt*64+nt*16+quad*4+i]
      v4f sc[4];
      __builtin_amdgcn_s_setprio(1);
#pragma unroll
      for (int nt = 0; nt < 4; nt++) {
        const unsigned short* kp = &KsB[(nt * 16 + l16) * 72 + quad * 8];
        v8s k0 = *(const v8s*)kp;
        v8s k1 = *(const v8s*)(kp + 32);
        v4f z = (v4f){0.f, 0.f, 0.f, 0.f};
        z = __builtin_amdgcn_mfma_f32_16x16x32_bf16(k0, aQ[0], z, 0, 0, 0);
        z = __builtin_amdgcn_mfma_f32_16x16x32_bf16(k1, aQ[1], z, 0, 0, 0);
        sc[nt] = z;
      }
      __builtin_amdgcn_s_setprio(0);

      // scale + causal (additive) + padding (replace) — exact ref semantics
#pragma unroll
      for (int nt = 0; nt < 4; nt++) {
#pragma unroll
        for (int i = 0; i < 4; i++) {
          int kid = nt * 16 + quad * 4 + i;
          int key = kt * 64 + kid;
          float v = sc[nt][i] * 0.125f;
          v += (mf && (key > qrow_l)) ? NEGV : 0.f;
          v = ((mk >> kid) & 1ull) ? v : NEGV;
          sc[nt][i] = v;
        }
      }

      // row max: 15 in-lane fmax + 2 cross-quad shuffles (row = l16)
      float mx;
      {
        float a = fmaxf(fmaxf(sc[0][0], sc[0][1]), fmaxf(sc[0][2], sc[0][3]));
        float b2 = fmaxf(fmaxf(sc[1][0], sc[1][1]), fmaxf(sc[1][2], sc[1][3]));
        float c = fmaxf(fmaxf(sc[2][0], sc[2][1]), fmaxf(sc[2][2], sc[2][3]));
        float d = fmaxf(fmaxf(sc[3][0], sc[3][1]), fmaxf(sc[3][2], sc[3][3]));
        mx = fmaxf(fmaxf(a, b2), fmaxf(c, d));
      }
      mx = fmaxf(mx, __shfl_xor(mx, 16));
      mx = fmaxf(mx, __shfl_xor(mx, 32));

      // T13 defer-max (exact: row-uniform scale cancels in normalize)
      if (!__all(mx - m_i <= 8.0f)) {
        float mnew = fmaxf(m_i, mx);
        float alpha = __expf(m_i - mnew);
        m_i = mnew;
        float a0 = __shfl(alpha, quad * 4 + 0);
        float a1 = __shfl(alpha, quad * 4 + 1);
        float a2 = __shfl(alpha, quad * 4 + 2);
        float a3 = __shfl(alpha, quad * 4 + 3);
#pragma unroll
        for (int dt = 0; dt < 4; dt++) {
          accO[dt][0] *= a0; accO[dt][1] *= a1;
          accO[dt][2] *= a2; accO[dt][3] *= a3;
        }
        accL[0] *= a0; accL[1] *= a1; accL[2] *= a2; accL[3] *= a3;
      }

      // exp + pack to bf16 pairs + 4x ds_write_b64 into P[qrow l16][key]
#pragma unroll
      for (int nt = 0; nt < 4; nt++) {
#pragma unroll
        for (int i = 0; i < 4; i++)
          sc[nt][i] = __expf(sc[nt][i] - m_i);
        uint2 w;
        w.x = cvt_pk_bf16(sc[nt][0], sc[nt][1]);
        w.y = cvt_pk_bf16(sc[nt][2], sc[nt][3]);
        *(uint2*)&Ps[wave][l16 * 72 + nt * 16 + quad * 4] = w;
      }

      __builtin_amdgcn_s_setprio(1);
#pragma unroll
      for (int ks = 0; ks < 2; ks++) {
        v8s aP = *(const v8s*)&Ps[wave][l16 * 72 + ks * 32 + quad * 8];
        accL = __builtin_amdgcn_mfma_f32_16x16x32_bf16(aP, ones, accL, 0, 0, 0);
#pragma unroll
        for (int dt = 0; dt < 4; dt++) {
          v8s bV = *(const v8s*)&VtB[(dt * 16 + l16) * 72 + ks * 32 + quad * 8];
          accO[dt] =
              __builtin_amdgcn_mfma_f32_16x16x32_bf16(aP, bV, accO[dt], 0, 0, 0);
        }
      }
      __builtin_amdgcn_s_setprio(0);
    }
    if (phase == 0) __syncthreads();  // all waves done before flag vote
  }

  // normalize + store O bf16 head-major over own Q region (in place)
#pragma unroll
  for (int i = 0; i < 4; i++) {
    float inv = 1.f / accL[i];
    int qr = qbase_D + i;
    size_t base = head_off + (size_t)qr * HD;
#pragma unroll
    for (int dt = 0; dt < 4; dt++)
      o[base + dt * 16 + l16] = f2bf(accO[dt][i] * inv);
  }
}

// ---------------------------------------------------------------- launch
extern "C" void kernel_launch(void* const* d_in, const int* in_sizes, int n_in,
                              void* d_out, int out_size, void* d_ws, size_t ws_size,
                              hipStream_t stream) {
  const float* q  = (const float*)d_in[0];
  const float* k  = (const float*)d_in[1];
  const float* v  = (const float*)d_in[2];
  const int* amask = (const int*)d_in[3];
  const float* Wq = (const float*)d_in[4];
  const float* Wk = (const float*)d_in[5];
  const float* Wv = (const float*)d_in[6];
  const float* Wo = (const float*)d_in[7];
  const int* mf  = (const int*)d_in[8];
  float* out = (float*)d_out;

  unsigned short* ws = (unsigned short*)d_ws;
  unsigned short* qh = ws;                  // O overwrites qh after attention
  unsigned short* kh = qh + 3145728;
  unsigned short* vh = kh + 3145728;
  unsigned short* wqt = vh + 3145728;
  unsigned short* wkt = wqt + 589824;
  unsigned short* wvt = wkt + 589824;
  unsigned short* wot = wvt + 589824;
  // vht (6.3 MB bf16) lives in d_out (12.6 MB) — dead until gemm_o overwrites.
  unsigned short* vht = (unsigned short*)d_out;

  transpose_w<<<dim3(24, 24, 4), 256, 0, stream>>>(Wq, Wk, Wv, Wo,
                                                   wqt, wkt, wvt, wot);
  gemm_qkv<<<dim3(32, 6, 3), 256, 0, stream>>>(q, k, v, wqt, wkt, wvt,
                                               qh, kh, vh);
  transpose_vh<<<dim3(64, 2, 24), 256, 0, stream>>>(vh, vht);
  attn_kernel<<<dim3(32, 24), 256, 0, stream>>>(qh, kh, vht, amask, mf, qh);
  gemm_o<<<dim3(32, 6), 256, 0, stream>>>(qh, wot, out);
}